// Round 3
// baseline (1092.699 us; speedup 1.0000x reference)
//
#include <hip/hip_runtime.h>
#include <stdint.h>

typedef __bf16  bf16x8  __attribute__((ext_vector_type(8)));
typedef float   floatx4 __attribute__((ext_vector_type(4)));

typedef __attribute__((address_space(1))) void gvoid_t;
typedef __attribute__((address_space(3))) void svoid_t;

// async global->LDS, 16B per lane; lds must be wave-uniform base (HW adds lane*16)
__device__ __forceinline__ void gld16(ushort* lds, const ushort* g) {
  __builtin_amdgcn_global_load_lds((gvoid_t*)g, (svoid_t*)lds, 16, 0, 0);
}

__device__ __forceinline__ ushort f2bf(float f) {
  union { float f; unsigned u; } v; v.f = f;
  unsigned u = v.u;
  return (ushort)((u + 0x7fffu + ((u >> 16) & 1u)) >> 16);  // RNE
}
__device__ __forceinline__ float bf2f(ushort h) {
  union { unsigned u; float f; } v; v.u = ((unsigned)h) << 16; return v.f;
}

__device__ __forceinline__ float qmax16(float v) {
  v = fmaxf(v, __shfl_xor(v, 1));
  v = fmaxf(v, __shfl_xor(v, 2));
  v = fmaxf(v, __shfl_xor(v, 4));
  v = fmaxf(v, __shfl_xor(v, 8));
  return v;
}
__device__ __forceinline__ float qsum16(float v) {
  v += __shfl_xor(v, 1);
  v += __shfl_xor(v, 2);
  v += __shfl_xor(v, 4);
  v += __shfl_xor(v, 8);
  return v;
}

// ---------------------------------------------------------------- convert
// fp32 -> bf16, 4 elements/thread
__global__ __launch_bounds__(256) void cvt_f32_bf16(
    const float* __restrict__ in, ushort* __restrict__ out) {
  int i = blockIdx.x * 256 + threadIdx.x;
  float4 a = ((const float4*)in)[i];
  ushort4 o;
  o.x = f2bf(a.x); o.y = f2bf(a.y); o.z = f2bf(a.z); o.w = f2bf(a.w);
  ((ushort4*)out)[i] = o;
}

// ---------------------------------------------------------------- transpose
// out[C][R](bf16) = in[R][C](fp32)^T, 64x64 tiles
__global__ __launch_bounds__(256) void transpose_cvt(
    const float* __restrict__ in, ushort* __restrict__ out, int R, int C) {
  __shared__ ushort tile[64][65];
  const int r0 = blockIdx.y * 64, c0 = blockIdx.x * 64;
  const int t = threadIdx.x;
#pragma unroll
  for (int rep = 0; rep < 16; rep++) {
    int idx = rep * 256 + t;
    int r = idx >> 6, c = idx & 63;
    tile[r][c] = f2bf(in[(size_t)(r0 + r) * C + c0 + c]);
  }
  __syncthreads();
#pragma unroll
  for (int rep = 0; rep < 16; rep++) {
    int idx = rep * 256 + t;
    int r = idx >> 6, c = idx & 63;
    out[(size_t)(c0 + r) * R + r0 + c] = tile[c][r];
  }
}

// ---------------------------------------------------------------- GEMM
// C[M][N] = A[M][K] * Bt[N][K]^T, 128x128 tile, BK=64, bf16 in, fp32 acc.
// EPI 0: fp32 C store to Cf. EPI 1: scatter QKV (N=6144): Q,K -> [bh][s][128],
// V -> V^T [bh][128][s] (bf16).
template <int EPI>
__global__ __launch_bounds__(256) void gemm128(
    const ushort* __restrict__ A, const ushort* __restrict__ Bt,
    float* __restrict__ Cf,
    ushort* __restrict__ C0, ushort* __restrict__ C1, ushort* __restrict__ C2,
    int M, int N, int K) {
  __shared__ __align__(16) ushort As[128 * 64];
  __shared__ __align__(16) ushort Bs[128 * 64];
  const int t = threadIdx.x;
  const int lane = t & 63;
  const int w = t >> 6;
  const int l15 = lane & 15;
  const int quad = lane >> 4;
  const int m0 = blockIdx.y * 128;
  const int n0 = blockIdx.x * 128;
  const int wm = (w >> 1) * 64;
  const int wn = (w & 1) * 64;

  floatx4 acc[4][4];
  const floatx4 zero = {0.f, 0.f, 0.f, 0.f};
#pragma unroll
  for (int i = 0; i < 4; i++)
#pragma unroll
    for (int j = 0; j < 4; j++) acc[i][j] = zero;

  for (int kb = 0; kb < K; kb += 64) {
    __syncthreads();
    // stage A,B tiles (128 rows x 64 k). rows of 8 16B-chunks, chunk swizzled
    // by XOR(row&7) so fragment reads are ~conflict-free.
#pragma unroll
    for (int it = 0; it < 4; it++) {
      int o = (w * 4 + it) * 64 + lane;  // chunk 0..1023
      int row = o >> 3;
      int c = (o & 7) ^ (row & 7);
      gld16(&As[(w * 4 + it) * 512], A + (size_t)(m0 + row) * K + kb + c * 8);
      gld16(&Bs[(w * 4 + it) * 512], Bt + (size_t)(n0 + row) * K + kb + c * 8);
    }
    __syncthreads();
#pragma unroll
    for (int kk = 0; kk < 2; kk++) {
      bf16x8 af[4], bf[4];
#pragma unroll
      for (int i = 0; i < 4; i++) {
        int row = wm + i * 16 + l15;
        int c = (kk * 4 + quad) ^ (row & 7);
        af[i] = *(const bf16x8*)&As[row * 64 + c * 8];
      }
#pragma unroll
      for (int j = 0; j < 4; j++) {
        int row = wn + j * 16 + l15;
        int c = (kk * 4 + quad) ^ (row & 7);
        bf[j] = *(const bf16x8*)&Bs[row * 64 + c * 8];
      }
#pragma unroll
      for (int i = 0; i < 4; i++)
#pragma unroll
        for (int j = 0; j < 4; j++)
          acc[i][j] = __builtin_amdgcn_mfma_f32_16x16x32_bf16(af[i], bf[j],
                                                              acc[i][j], 0, 0, 0);
    }
  }

  if (EPI == 0) {
#pragma unroll
    for (int i = 0; i < 4; i++)
#pragma unroll
      for (int j = 0; j < 4; j++)
#pragma unroll
        for (int r = 0; r < 4; r++) {
          int m = m0 + wm + i * 16 + quad * 4 + r;
          int n = n0 + wn + j * 16 + l15;
          Cf[(size_t)m * N + n] = acc[i][j][r];
        }
  } else {
    // block covers exactly one (qkv, head): n0 is a multiple of 128
    const int qkvsel = n0 >> 11;
    const int h = (n0 >> 7) & 15;
#pragma unroll
    for (int i = 0; i < 4; i++)
#pragma unroll
      for (int j = 0; j < 4; j++) {
        int d = wn + j * 16 + l15;  // 0..127 within head
        if (qkvsel < 2) {
          ushort* dst = (qkvsel == 0) ? C0 : C1;
#pragma unroll
          for (int r = 0; r < 4; r++) {
            int m = m0 + wm + i * 16 + quad * 4 + r;
            int b = m >> 11, s = m & 2047;
            dst[((size_t)(b * 16 + h) * 2048 + s) * 128 + d] = f2bf(acc[i][j][r]);
          }
        } else {
          int m = m0 + wm + i * 16 + quad * 4;
          int b = m >> 11, s = m & 2047;
          ushort4 pk;
          pk.x = f2bf(acc[i][j][0]);
          pk.y = f2bf(acc[i][j][1]);
          pk.z = f2bf(acc[i][j][2]);
          pk.w = f2bf(acc[i][j][3]);
          *(ushort4*)&C2[((size_t)(b * 16 + h) * 128 + d) * 2048 + s] = pk;
        }
      }
  }
}

// ---------------------------------------------------------------- RoPE
// in-place on Q and K planes: [bh][s][128], pair (d, d+64), d<64. cos/sin fp32.
__global__ __launch_bounds__(256) void rope_kernel(
    ushort* __restrict__ Q, ushort* __restrict__ Kb,
    const float* __restrict__ cosT, const float* __restrict__ sinT) {
  unsigned gid = blockIdx.x * 256u + threadIdx.x;
  int d = gid & 63;
  int s = (gid >> 6) & 2047;
  int bh = (gid >> 17) & 63;
  ushort* buf = (gid >> 23) ? Kb : Q;
  size_t base = ((size_t)bh * 2048 + s) * 128;
  float x1 = bf2f(buf[base + d]);
  float x2 = bf2f(buf[base + d + 64]);
  float c = cosT[s * 64 + d];
  float sn = sinT[s * 64 + d];
  buf[base + d] = f2bf(x1 * c - x2 * sn);
  buf[base + d + 64] = f2bf(x1 * sn + x2 * c);
}

// ---------------------------------------------------------------- attention
// flash-style causal attention. grid = (S/128 q-tiles, B*H). block = 4 waves.
// Q [bh][s][128], K [bh][s][128], VT [bh][128][s], O -> [b][s][h*128+d] (bf16)
__global__ __launch_bounds__(256) void attn_kernel(
    const ushort* __restrict__ Q, const ushort* __restrict__ Kb,
    const ushort* __restrict__ VT, ushort* __restrict__ O) {
  __shared__ __align__(16) ushort Ks[64 * 128];  // [k_local][d], xor(row&15)
  __shared__ __align__(16) ushort Vs[128 * 64];  // [d][s_local], xor(row&7)
  __shared__ __align__(16) ushort Ps[128 * 64];  // [q_local][k_local], xor(row&7)
  const int t = threadIdx.x, lane = t & 63, w = t >> 6;
  const int l15 = lane & 15, quad = lane >> 4;
  const int tq = blockIdx.x, bh = blockIdx.y;
  const int wr0 = tq * 128 + w * 32;  // this wave's first q row
  const size_t hbase = (size_t)bh * 2048 * 128;
  const float NEGINF = -__builtin_inff();

  // Q fragments: rows wr0..wr0+31, full hd=128
  bf16x8 aq[2][4];
#pragma unroll
  for (int i = 0; i < 2; i++)
#pragma unroll
    for (int kb = 0; kb < 4; kb++)
      aq[i][kb] = *(const bf16x8*)&Q[hbase + (size_t)(wr0 + i * 16 + l15) * 128 +
                                     kb * 32 + quad * 8];

  float m2[2][4], lsum[2][4];
  floatx4 oacc[2][8];
  const floatx4 zero = {0.f, 0.f, 0.f, 0.f};
#pragma unroll
  for (int i = 0; i < 2; i++) {
#pragma unroll
    for (int r = 0; r < 4; r++) { m2[i][r] = NEGINF; lsum[i][r] = 0.f; }
#pragma unroll
    for (int dj = 0; dj < 8; dj++) oacc[i][dj] = zero;
  }

  const float sl2e = 0.08838834764831845f * 1.4426950408889634f;  // scale*log2e
  const int ntk = 2 * tq + 2;

  for (int tk = 0; tk < ntk; tk++) {
    __syncthreads();
#pragma unroll
    for (int it = 0; it < 4; it++) {
      int o = (w * 4 + it) * 64 + lane;
      {  // K tile: 64 rows x 128 el
        int row = o >> 4;
        int c = (o & 15) ^ (row & 15);
        gld16(&Ks[(w * 4 + it) * 512],
              Kb + hbase + (size_t)(tk * 64 + row) * 128 + c * 8);
      }
      {  // V^T tile: 128 rows x 64 el
        int row = o >> 3;
        int c = (o & 7) ^ (row & 7);
        gld16(&Vs[(w * 4 + it) * 512],
              VT + hbase + (size_t)row * 2048 + tk * 64 + c * 8);
      }
    }
    __syncthreads();

    const bool active = (tk * 64) <= (wr0 + 31);
    if (active) {
      floatx4 sacc[2][4];
#pragma unroll
      for (int i = 0; i < 2; i++)
#pragma unroll
        for (int j = 0; j < 4; j++) sacc[i][j] = zero;
#pragma unroll
      for (int kb = 0; kb < 4; kb++) {
        bf16x8 bk[4];
#pragma unroll
        for (int j = 0; j < 4; j++) {
          int row = j * 16 + l15;
          int c = (kb * 4 + quad) ^ (row & 15);
          bk[j] = *(const bf16x8*)&Ks[row * 128 + c * 8];
        }
#pragma unroll
        for (int i = 0; i < 2; i++)
#pragma unroll
          for (int j = 0; j < 4; j++)
            sacc[i][j] = __builtin_amdgcn_mfma_f32_16x16x32_bf16(
                aq[i][kb], bk[j], sacc[i][j], 0, 0, 0);
      }
      const bool need_mask = (tk * 64 + 63) > wr0;
#pragma unroll
      for (int i = 0; i < 2; i++)
#pragma unroll
        for (int j = 0; j < 4; j++)
#pragma unroll
          for (int r = 0; r < 4; r++) {
            float v = sacc[i][j][r] * sl2e;
            if (need_mask) {
              int col = tk * 64 + j * 16 + l15;
              int row = wr0 + i * 16 + quad * 4 + r;
              if (col > row) v = NEGINF;
            }
            sacc[i][j][r] = v;
          }
#pragma unroll
      for (int i = 0; i < 2; i++)
#pragma unroll
        for (int r = 0; r < 4; r++) {
          float mx = fmaxf(fmaxf(sacc[i][0][r], sacc[i][1][r]),
                           fmaxf(sacc[i][2][r], sacc[i][3][r]));
          mx = qmax16(mx);
          float mnew = fmaxf(m2[i][r], mx);
          float alpha = __builtin_exp2f(m2[i][r] - mnew);
          m2[i][r] = mnew;
          float rs = 0.f;
#pragma unroll
          for (int j = 0; j < 4; j++) {
            float p = __builtin_exp2f(sacc[i][j][r] - mnew);
            sacc[i][j][r] = p;
            rs += p;
          }
          rs = qsum16(rs);
          lsum[i][r] = lsum[i][r] * alpha + rs;
#pragma unroll
          for (int dj = 0; dj < 8; dj++) oacc[i][dj][r] *= alpha;
        }
      // write P (bf16) to per-wave LDS region
#pragma unroll
      for (int i = 0; i < 2; i++)
#pragma unroll
        for (int j = 0; j < 4; j++)
#pragma unroll
          for (int r = 0; r < 4; r++) {
            int prow = w * 32 + i * 16 + quad * 4 + r;
            int col = j * 16 + l15;
            int scol = (((col >> 3) ^ (prow & 7)) << 3) | (col & 7);
            Ps[prow * 64 + scol] = f2bf(sacc[i][j][r]);
          }
    }
    __syncthreads();
    if (active) {
      bf16x8 ap[2][2];
#pragma unroll
      for (int i = 0; i < 2; i++)
#pragma unroll
        for (int kk = 0; kk < 2; kk++) {
          int row = w * 32 + i * 16 + l15;
          int c = (kk * 4 + quad) ^ (row & 7);
          ap[i][kk] = *(const bf16x8*)&Ps[row * 64 + c * 8];
        }
#pragma unroll
      for (int kk = 0; kk < 2; kk++)
#pragma unroll
        for (int dj = 0; dj < 8; dj++) {
          int rowd = dj * 16 + l15;
          int c = (kk * 4 + quad) ^ (rowd & 7);
          bf16x8 bv = *(const bf16x8*)&Vs[rowd * 64 + c * 8];
#pragma unroll
          for (int i = 0; i < 2; i++)
            oacc[i][dj] = __builtin_amdgcn_mfma_f32_16x16x32_bf16(
                ap[i][kk], bv, oacc[i][dj], 0, 0, 0);
        }
    }
  }

  // epilogue: O[b][q][h*128+d]
  const int b = bh >> 4, h = bh & 15;
#pragma unroll
  for (int i = 0; i < 2; i++) {
    float rinv[4];
#pragma unroll
    for (int r = 0; r < 4; r++) rinv[r] = 1.0f / lsum[i][r];
#pragma unroll
    for (int dj = 0; dj < 8; dj++) {
      int d = dj * 16 + l15;
#pragma unroll
      for (int r = 0; r < 4; r++) {
        int q = wr0 + i * 16 + quad * 4 + r;
        O[((size_t)(b * 2048 + q)) * 2048 + h * 128 + d] =
            f2bf(oacc[i][dj][r] * rinv[r]);
      }
    }
  }
}

// ---------------------------------------------------------------- launch
// All inputs/outputs fp32 (per reference). bf16 scratch:
//   d_out[0 .. 33.5MB)  : xbf (bf16 x), dead before GEMM2 overwrites d_out
//   ws[0, 33.5M)        : wqkvT (GEMM1 only) then Ob (attn -> GEMM2)
//   ws[33.5M, 42.0M)    : woutT
//   ws[42.0M, 75.5M)    : Q   [64][2048][128]
//   ws[75.5M, 109.1M)   : K   [64][2048][128]
//   ws[109.1M, 142.6M)  : VT  [64][128][2048]
// total ws: 142,606,336 B
extern "C" void kernel_launch(void* const* d_in, const int* in_sizes, int n_in,
                              void* d_out, int out_size, void* d_ws, size_t ws_size,
                              hipStream_t stream) {
  const float* x    = (const float*)d_in[0];
  const float* cosT = (const float*)d_in[1];
  const float* sinT = (const float*)d_in[2];
  const float* wqkv = (const float*)d_in[3];
  const float* wout = (const float*)d_in[4];
  float* out = (float*)d_out;
  char* ws = (char*)d_ws;

  ushort* xbf   = (ushort*)d_out;                      // 8192x2048 bf16 scratch
  ushort* wqkvT = (ushort*)(ws);                       // 6144x2048
  ushort* Ob    = (ushort*)(ws);                       // 8192x2048 (after GEMM1)
  ushort* woutT = (ushort*)(ws + 33554432);            // 2048x2048
  ushort* Qb    = (ushort*)(ws + 41943040);
  ushort* Kbuf  = (ushort*)(ws + 75497472);
  ushort* VTb   = (ushort*)(ws + 109051904);

  cvt_f32_bf16<<<16384, 256, 0, stream>>>(x, xbf);
  transpose_cvt<<<dim3(96, 32), 256, 0, stream>>>(wqkv, wqkvT, 2048, 6144);
  transpose_cvt<<<dim3(32, 32), 256, 0, stream>>>(wout, woutT, 2048, 2048);
  gemm128<1><<<dim3(48, 64), 256, 0, stream>>>(xbf, wqkvT, nullptr,
                                               Qb, Kbuf, VTb, 8192, 6144, 2048);
  rope_kernel<<<65536, 256, 0, stream>>>(Qb, Kbuf, cosT, sinT);
  attn_kernel<<<dim3(16, 64), 256, 0, stream>>>(Qb, Kbuf, VTb, Ob);
  gemm128<0><<<dim3(16, 64), 256, 0, stream>>>(Ob, woutT, out,
                                               nullptr, nullptr, nullptr,
                                               8192, 2048, 2048);
}

// Round 4
// 730.023 us; speedup vs baseline: 1.4968x; 1.4968x over previous
//
#include <hip/hip_runtime.h>
#include <stdint.h>

typedef __bf16  bf16x8  __attribute__((ext_vector_type(8)));
typedef float   floatx4 __attribute__((ext_vector_type(4)));

typedef __attribute__((address_space(1))) void gvoid_t;
typedef __attribute__((address_space(3))) void svoid_t;

// async global->LDS, 16B per lane; lds must be wave-uniform base (HW adds lane*16)
__device__ __forceinline__ void gld16(ushort* lds, const ushort* g) {
  __builtin_amdgcn_global_load_lds((gvoid_t*)g, (svoid_t*)lds, 16, 0, 0);
}

__device__ __forceinline__ ushort f2bf(float f) {
  union { float f; unsigned u; } v; v.f = f;
  unsigned u = v.u;
  return (ushort)((u + 0x7fffu + ((u >> 16) & 1u)) >> 16);  // RNE
}
__device__ __forceinline__ float bf2f(ushort h) {
  union { unsigned u; float f; } v; v.u = ((unsigned)h) << 16; return v.f;
}

__device__ __forceinline__ float qmax16(float v) {
  v = fmaxf(v, __shfl_xor(v, 1));
  v = fmaxf(v, __shfl_xor(v, 2));
  v = fmaxf(v, __shfl_xor(v, 4));
  v = fmaxf(v, __shfl_xor(v, 8));
  return v;
}
__device__ __forceinline__ float qsum16(float v) {
  v += __shfl_xor(v, 1);
  v += __shfl_xor(v, 2);
  v += __shfl_xor(v, 4);
  v += __shfl_xor(v, 8);
  return v;
}

// ---------------------------------------------------------------- convert
__global__ __launch_bounds__(256) void cvt_f32_bf16(
    const float* __restrict__ in, ushort* __restrict__ out) {
  int i = blockIdx.x * 256 + threadIdx.x;
  float4 a = ((const float4*)in)[i];
  ushort4 o;
  o.x = f2bf(a.x); o.y = f2bf(a.y); o.z = f2bf(a.z); o.w = f2bf(a.w);
  ((ushort4*)out)[i] = o;
}

// ---------------------------------------------------------------- transpose
// out[C][R](bf16) = in[R][C](fp32)^T, 64x64 tiles
__global__ __launch_bounds__(256) void transpose_cvt(
    const float* __restrict__ in, ushort* __restrict__ out, int R, int C) {
  __shared__ ushort tile[64][65];
  const int r0 = blockIdx.y * 64, c0 = blockIdx.x * 64;
  const int t = threadIdx.x;
#pragma unroll
  for (int rep = 0; rep < 16; rep++) {
    int idx = rep * 256 + t;
    int r = idx >> 6, c = idx & 63;
    tile[r][c] = f2bf(in[(size_t)(r0 + r) * C + c0 + c]);
  }
  __syncthreads();
#pragma unroll
  for (int rep = 0; rep < 16; rep++) {
    int idx = rep * 256 + t;
    int r = idx >> 6, c = idx & 63;
    out[(size_t)(c0 + r) * R + r0 + c] = tile[c][r];
  }
}

// ---------------------------------------------------------------- GEMM
// C[M][N] = A[M][K] * Bt[N][K]^T, 128x128 tile, BK=64, bf16 in, fp32 acc.
// EPI 0: fp32 C store to Cf. EPI 1: scatter QKV (N=6144): Q,K -> [bh][s][128],
// V -> V^T [bh][128][s] (bf16).
template <int EPI>
__global__ __launch_bounds__(256) void gemm128(
    const ushort* __restrict__ A, const ushort* __restrict__ Bt,
    float* __restrict__ Cf,
    ushort* __restrict__ C0, ushort* __restrict__ C1, ushort* __restrict__ C2,
    int M, int N, int K) {
  __shared__ __align__(16) ushort As[128 * 64];
  __shared__ __align__(16) ushort Bs[128 * 64];
  const int t = threadIdx.x;
  const int lane = t & 63;
  const int w = t >> 6;
  const int l15 = lane & 15;
  const int quad = lane >> 4;
  const int m0 = blockIdx.y * 128;
  const int n0 = blockIdx.x * 128;
  const int wm = (w >> 1) * 64;
  const int wn = (w & 1) * 64;

  floatx4 acc[4][4];
  const floatx4 zero = {0.f, 0.f, 0.f, 0.f};
#pragma unroll
  for (int i = 0; i < 4; i++)
#pragma unroll
    for (int j = 0; j < 4; j++) acc[i][j] = zero;

  for (int kb = 0; kb < K; kb += 64) {
    __syncthreads();
#pragma unroll
    for (int it = 0; it < 4; it++) {
      int o = (w * 4 + it) * 64 + lane;  // chunk 0..1023
      int row = o >> 3;
      int c = (o & 7) ^ (row & 7);
      gld16(&As[(w * 4 + it) * 512], A + (size_t)(m0 + row) * K + kb + c * 8);
      gld16(&Bs[(w * 4 + it) * 512], Bt + (size_t)(n0 + row) * K + kb + c * 8);
    }
    __syncthreads();
#pragma unroll
    for (int kk = 0; kk < 2; kk++) {
      bf16x8 af[4], bf[4];
#pragma unroll
      for (int i = 0; i < 4; i++) {
        int row = wm + i * 16 + l15;
        int c = (kk * 4 + quad) ^ (row & 7);
        af[i] = *(const bf16x8*)&As[row * 64 + c * 8];
      }
#pragma unroll
      for (int j = 0; j < 4; j++) {
        int row = wn + j * 16 + l15;
        int c = (kk * 4 + quad) ^ (row & 7);
        bf[j] = *(const bf16x8*)&Bs[row * 64 + c * 8];
      }
#pragma unroll
      for (int i = 0; i < 4; i++)
#pragma unroll
        for (int j = 0; j < 4; j++)
          acc[i][j] = __builtin_amdgcn_mfma_f32_16x16x32_bf16(af[i], bf[j],
                                                              acc[i][j], 0, 0, 0);
    }
  }

  if (EPI == 0) {
#pragma unroll
    for (int i = 0; i < 4; i++)
#pragma unroll
      for (int j = 0; j < 4; j++)
#pragma unroll
        for (int r = 0; r < 4; r++) {
          int m = m0 + wm + i * 16 + quad * 4 + r;
          int n = n0 + wn + j * 16 + l15;
          Cf[(size_t)m * N + n] = acc[i][j][r];
        }
  } else {
    const int qkvsel = n0 >> 11;
    const int h = (n0 >> 7) & 15;
#pragma unroll
    for (int i = 0; i < 4; i++)
#pragma unroll
      for (int j = 0; j < 4; j++) {
        int d = wn + j * 16 + l15;  // 0..127 within head
        if (qkvsel < 2) {
          ushort* dst = (qkvsel == 0) ? C0 : C1;
#pragma unroll
          for (int r = 0; r < 4; r++) {
            int m = m0 + wm + i * 16 + quad * 4 + r;
            int b = m >> 11, s = m & 2047;
            dst[((size_t)(b * 16 + h) * 2048 + s) * 128 + d] = f2bf(acc[i][j][r]);
          }
        } else {
          int m = m0 + wm + i * 16 + quad * 4;
          int b = m >> 11, s = m & 2047;
          ushort4 pk;
          pk.x = f2bf(acc[i][j][0]);
          pk.y = f2bf(acc[i][j][1]);
          pk.z = f2bf(acc[i][j][2]);
          pk.w = f2bf(acc[i][j][3]);
          *(ushort4*)&C2[((size_t)(b * 16 + h) * 128 + d) * 2048 + s] = pk;
        }
      }
  }
}

// ---------------------------------------------------------------- RoPE
__global__ __launch_bounds__(256) void rope_kernel(
    ushort* __restrict__ Q, ushort* __restrict__ Kb,
    const float* __restrict__ cosT, const float* __restrict__ sinT) {
  unsigned gid = blockIdx.x * 256u + threadIdx.x;
  int d = gid & 63;
  int s = (gid >> 6) & 2047;
  int bh = (gid >> 17) & 63;
  ushort* buf = (gid >> 23) ? Kb : Q;
  size_t base = ((size_t)bh * 2048 + s) * 128;
  float x1 = bf2f(buf[base + d]);
  float x2 = bf2f(buf[base + d + 64]);
  float c = cosT[s * 64 + d];
  float sn = sinT[s * 64 + d];
  buf[base + d] = f2bf(x1 * c - x2 * sn);
  buf[base + d + 64] = f2bf(x1 * sn + x2 * c);
}

// ---------------------------------------------------------------- attention
// flash-style causal attention. Grid: 1-D, 2048 blocks, heavy-first:
//   bid -> tq = 31 - (bid>>6), bh = bid & 63. Q-tile = 64 rows, 4 waves x 16.
// Q [bh][s][128], K [bh][s][128], VT [bh][128][s], O -> [b][s][h*128+d] (bf16)
__global__ __launch_bounds__(256, 4) void attn_kernel(
    const ushort* __restrict__ Q, const ushort* __restrict__ Kb,
    const ushort* __restrict__ VT, ushort* __restrict__ O) {
  __shared__ __align__(16) ushort Ks[64 * 128];  // [k_local][d], xor(row&15)
  __shared__ __align__(16) ushort Vs[128 * 64];  // [d][s_local], xor(row&7)
  __shared__ __align__(16) ushort Ps[64 * 64];   // [q_local][k_local], xor(row&7)
  const int t = threadIdx.x, lane = t & 63, w = t >> 6;
  const int l15 = lane & 15, quad = lane >> 4;
  const int bid = blockIdx.x;
  const int tq = 31 - (bid >> 6);   // heavy-first
  const int bh = bid & 63;
  const int q0 = tq * 64 + w * 16;  // this wave's first q row
  const size_t hbase = (size_t)bh * 2048 * 128;
  const float NEGINF = -__builtin_inff();

  // Q fragments: rows q0..q0+15, full hd=128
  bf16x8 aq[4];
#pragma unroll
  for (int kb = 0; kb < 4; kb++)
    aq[kb] = *(const bf16x8*)&Q[hbase + (size_t)(q0 + l15) * 128 +
                                kb * 32 + quad * 8];

  float m2[4], lsum[4];
  floatx4 oacc[8];
  const floatx4 zero = {0.f, 0.f, 0.f, 0.f};
#pragma unroll
  for (int r = 0; r < 4; r++) { m2[r] = NEGINF; lsum[r] = 0.f; }
#pragma unroll
  for (int dj = 0; dj < 8; dj++) oacc[dj] = zero;

  const float sl2e = 0.08838834764831845f * 1.4426950408889634f;  // scale*log2e
  const int ntk = tq + 1;

  for (int tk = 0; tk < ntk; tk++) {
    __syncthreads();
#pragma unroll
    for (int it = 0; it < 4; it++) {
      int o = (w * 4 + it) * 64 + lane;
      {  // K tile: 64 rows x 128 el
        int row = o >> 4;
        int c = (o & 15) ^ (row & 15);
        gld16(&Ks[(w * 4 + it) * 512],
              Kb + hbase + (size_t)(tk * 64 + row) * 128 + c * 8);
      }
      {  // V^T tile: 128 rows x 64 el
        int row = o >> 3;
        int c = (o & 7) ^ (row & 7);
        gld16(&Vs[(w * 4 + it) * 512],
              VT + hbase + (size_t)row * 2048 + tk * 64 + c * 8);
      }
    }
    __syncthreads();

    // ---- QK^T
    floatx4 sacc[4];
#pragma unroll
    for (int j = 0; j < 4; j++) sacc[j] = zero;
#pragma unroll
    for (int kb = 0; kb < 4; kb++) {
#pragma unroll
      for (int j = 0; j < 4; j++) {
        int row = j * 16 + l15;
        int c = (kb * 4 + quad) ^ (row & 15);
        bf16x8 bk = *(const bf16x8*)&Ks[row * 128 + c * 8];
        sacc[j] = __builtin_amdgcn_mfma_f32_16x16x32_bf16(aq[kb], bk, sacc[j],
                                                          0, 0, 0);
      }
    }

    // ---- mask + online softmax
    const bool need_mask = (tk == tq);
#pragma unroll
    for (int j = 0; j < 4; j++)
#pragma unroll
      for (int r = 0; r < 4; r++) {
        float v = sacc[j][r] * sl2e;
        if (need_mask) {
          int col = tk * 64 + j * 16 + l15;
          int row = q0 + quad * 4 + r;
          if (col > row) v = NEGINF;
        }
        sacc[j][r] = v;
      }
#pragma unroll
    for (int r = 0; r < 4; r++) {
      float mx = fmaxf(fmaxf(sacc[0][r], sacc[1][r]),
                       fmaxf(sacc[2][r], sacc[3][r]));
      mx = qmax16(mx);
      float mnew = fmaxf(m2[r], mx);
      float alpha = __builtin_exp2f(m2[r] - mnew);
      m2[r] = mnew;
      float rs = 0.f;
#pragma unroll
      for (int j = 0; j < 4; j++) {
        float p = __builtin_exp2f(sacc[j][r] - mnew);
        sacc[j][r] = p;
        rs += p;
      }
      rs = qsum16(rs);
      lsum[r] = lsum[r] * alpha + rs;
#pragma unroll
      for (int dj = 0; dj < 8; dj++) oacc[dj][r] *= alpha;
    }

    // ---- P -> LDS (bf16), per-wave rows [w*16, w*16+16)
#pragma unroll
    for (int j = 0; j < 4; j++)
#pragma unroll
      for (int r = 0; r < 4; r++) {
        int prow = w * 16 + quad * 4 + r;
        int col = j * 16 + l15;
        int scol = (((col >> 3) ^ (prow & 7)) << 3) | (col & 7);
        Ps[prow * 64 + scol] = f2bf(sacc[j][r]);
      }

    // ---- PV (no barrier needed: each wave reads only its own Ps rows,
    //      but Vs is block-shared and already synced at loop top)
    bf16x8 ap[2];
#pragma unroll
    for (int kk = 0; kk < 2; kk++) {
      int row = w * 16 + l15;
      int c = (kk * 4 + quad) ^ (row & 7);
      ap[kk] = *(const bf16x8*)&Ps[row * 64 + c * 8];
    }
#pragma unroll
    for (int kk = 0; kk < 2; kk++)
#pragma unroll
      for (int dj = 0; dj < 8; dj++) {
        int rowd = dj * 16 + l15;
        int c = (kk * 4 + quad) ^ (rowd & 7);
        bf16x8 bv = *(const bf16x8*)&Vs[rowd * 64 + c * 8];
        oacc[dj] = __builtin_amdgcn_mfma_f32_16x16x32_bf16(ap[kk], bv, oacc[dj],
                                                           0, 0, 0);
      }
  }

  // epilogue: O[b][q][h*128+d]
  const int b = bh >> 4, h = bh & 15;
  float rinv[4];
#pragma unroll
  for (int r = 0; r < 4; r++) rinv[r] = 1.0f / lsum[r];
#pragma unroll
  for (int dj = 0; dj < 8; dj++) {
    int d = dj * 16 + l15;
#pragma unroll
    for (int r = 0; r < 4; r++) {
      int q = q0 + quad * 4 + r;
      O[((size_t)(b * 2048 + q)) * 2048 + h * 128 + d] =
          f2bf(oacc[dj][r] * rinv[r]);
    }
  }
}

// ---------------------------------------------------------------- launch
// All inputs/outputs fp32 (per reference). bf16 scratch:
//   d_out[0 .. 33.5MB)  : xbf (bf16 x), dead before GEMM2 overwrites d_out
//   ws[0, 33.5M)        : wqkvT (GEMM1 only) then Ob (attn -> GEMM2)
//   ws[33.5M, 42.0M)    : woutT
//   ws[42.0M, 75.5M)    : Q   [64][2048][128]
//   ws[75.5M, 109.1M)   : K   [64][2048][128]
//   ws[109.1M, 142.6M)  : VT  [64][128][2048]
extern "C" void kernel_launch(void* const* d_in, const int* in_sizes, int n_in,
                              void* d_out, int out_size, void* d_ws, size_t ws_size,
                              hipStream_t stream) {
  const float* x    = (const float*)d_in[0];
  const float* cosT = (const float*)d_in[1];
  const float* sinT = (const float*)d_in[2];
  const float* wqkv = (const float*)d_in[3];
  const float* wout = (const float*)d_in[4];
  float* out = (float*)d_out;
  char* ws = (char*)d_ws;

  ushort* xbf   = (ushort*)d_out;                      // 8192x2048 bf16 scratch
  ushort* wqkvT = (ushort*)(ws);                       // 6144x2048
  ushort* Ob    = (ushort*)(ws);                       // 8192x2048 (after GEMM1)
  ushort* woutT = (ushort*)(ws + 33554432);            // 2048x2048
  ushort* Qb    = (ushort*)(ws + 41943040);
  ushort* Kbuf  = (ushort*)(ws + 75497472);
  ushort* VTb   = (ushort*)(ws + 109051904);

  cvt_f32_bf16<<<16384, 256, 0, stream>>>(x, xbf);
  transpose_cvt<<<dim3(96, 32), 256, 0, stream>>>(wqkv, wqkvT, 2048, 6144);
  transpose_cvt<<<dim3(32, 32), 256, 0, stream>>>(wout, woutT, 2048, 2048);
  gemm128<1><<<dim3(48, 64), 256, 0, stream>>>(xbf, wqkvT, nullptr,
                                               Qb, Kbuf, VTb, 8192, 6144, 2048);
  rope_kernel<<<65536, 256, 0, stream>>>(Qb, Kbuf, cosT, sinT);
  attn_kernel<<<2048, 256, 0, stream>>>(Qb, Kbuf, VTb, Ob);
  gemm128<0><<<dim3(16, 64), 256, 0, stream>>>(Ob, woutT, out,
                                               nullptr, nullptr, nullptr,
                                               8192, 2048, 2048);
}

// Round 5
// 636.967 us; speedup vs baseline: 1.7155x; 1.1461x over previous
//
#include <hip/hip_runtime.h>
#include <hip/hip_bf16.h>
#include <stdint.h>

typedef __bf16  bf16x8  __attribute__((ext_vector_type(8)));
typedef float   floatx4 __attribute__((ext_vector_type(4)));

typedef __attribute__((address_space(1))) void gvoid_t;
typedef __attribute__((address_space(3))) void svoid_t;

// async global->LDS, 16B per lane; lds must be wave-uniform base (HW adds lane*16)
__device__ __forceinline__ void gld16(ushort* lds, const ushort* g) {
  __builtin_amdgcn_global_load_lds((gvoid_t*)g, (svoid_t*)lds, 16, 0, 0);
}

__device__ __forceinline__ ushort f2bf(float f) {
  union { float f; unsigned u; } v; v.f = f;
  unsigned u = v.u;
  return (ushort)((u + 0x7fffu + ((u >> 16) & 1u)) >> 16);  // RNE
}
__device__ __forceinline__ float bf2f(ushort h) {
  union { unsigned u; float f; } v; v.u = ((unsigned)h) << 16; return v.f;
}
// pack two fp32 -> bf16x2 dword (RNE, HW v_cvt_pk when available)
__device__ __forceinline__ unsigned pk2bf(float a, float b) {
  __hip_bfloat162 h = __float22bfloat162_rn(make_float2(a, b));
  union { __hip_bfloat162 h; unsigned u; } v; v.h = h; return v.u;
}

// ---------------------------------------------------------------- convert
__global__ __launch_bounds__(256) void cvt_f32_bf16(
    const float* __restrict__ in, ushort* __restrict__ out) {
  int i = blockIdx.x * 256 + threadIdx.x;
  float4 a = ((const float4*)in)[i];
  ushort4 o;
  o.x = f2bf(a.x); o.y = f2bf(a.y); o.z = f2bf(a.z); o.w = f2bf(a.w);
  ((ushort4*)out)[i] = o;
}

// ---------------------------------------------------------------- transpose
// out[C][R](bf16) = in[R][C](fp32)^T, 64x64 tiles
__global__ __launch_bounds__(256) void transpose_cvt(
    const float* __restrict__ in, ushort* __restrict__ out, int R, int C) {
  __shared__ ushort tile[64][65];
  const int r0 = blockIdx.y * 64, c0 = blockIdx.x * 64;
  const int t = threadIdx.x;
#pragma unroll
  for (int rep = 0; rep < 16; rep++) {
    int idx = rep * 256 + t;
    int r = idx >> 6, c = idx & 63;
    tile[r][c] = f2bf(in[(size_t)(r0 + r) * C + c0 + c]);
  }
  __syncthreads();
#pragma unroll
  for (int rep = 0; rep < 16; rep++) {
    int idx = rep * 256 + t;
    int r = idx >> 6, c = idx & 63;
    out[(size_t)(c0 + r) * R + r0 + c] = tile[c][r];
  }
}

// ---------------------------------------------------------------- GEMM
// C[M][N] = A[M][K] * Bt[N][K]^T, 128x128 tile, BK=64, bf16 in, fp32 acc.
// EPI 0: fp32 C store to Cf. EPI 1: scatter QKV (N=6144): Q,K -> [bh][s][128],
// V -> V^T [bh][128][s] (bf16).
template <int EPI>
__global__ __launch_bounds__(256) void gemm128(
    const ushort* __restrict__ A, const ushort* __restrict__ Bt,
    float* __restrict__ Cf,
    ushort* __restrict__ C0, ushort* __restrict__ C1, ushort* __restrict__ C2,
    int M, int N, int K) {
  __shared__ __align__(16) ushort As[128 * 64];
  __shared__ __align__(16) ushort Bs[128 * 64];
  const int t = threadIdx.x;
  const int lane = t & 63;
  const int w = t >> 6;
  const int l15 = lane & 15;
  const int quad = lane >> 4;
  const int m0 = blockIdx.y * 128;
  const int n0 = blockIdx.x * 128;
  const int wm = (w >> 1) * 64;
  const int wn = (w & 1) * 64;

  floatx4 acc[4][4];
  const floatx4 zero = {0.f, 0.f, 0.f, 0.f};
#pragma unroll
  for (int i = 0; i < 4; i++)
#pragma unroll
    for (int j = 0; j < 4; j++) acc[i][j] = zero;

  for (int kb = 0; kb < K; kb += 64) {
    __syncthreads();
#pragma unroll
    for (int it = 0; it < 4; it++) {
      int o = (w * 4 + it) * 64 + lane;  // chunk 0..1023
      int row = o >> 3;
      int c = (o & 7) ^ (row & 7);
      gld16(&As[(w * 4 + it) * 512], A + (size_t)(m0 + row) * K + kb + c * 8);
      gld16(&Bs[(w * 4 + it) * 512], Bt + (size_t)(n0 + row) * K + kb + c * 8);
    }
    __syncthreads();
#pragma unroll
    for (int kk = 0; kk < 2; kk++) {
      bf16x8 af[4], bf[4];
#pragma unroll
      for (int i = 0; i < 4; i++) {
        int row = wm + i * 16 + l15;
        int c = (kk * 4 + quad) ^ (row & 7);
        af[i] = *(const bf16x8*)&As[row * 64 + c * 8];
      }
#pragma unroll
      for (int j = 0; j < 4; j++) {
        int row = wn + j * 16 + l15;
        int c = (kk * 4 + quad) ^ (row & 7);
        bf[j] = *(const bf16x8*)&Bs[row * 64 + c * 8];
      }
#pragma unroll
      for (int i = 0; i < 4; i++)
#pragma unroll
        for (int j = 0; j < 4; j++)
          acc[i][j] = __builtin_amdgcn_mfma_f32_16x16x32_bf16(af[i], bf[j],
                                                              acc[i][j], 0, 0, 0);
    }
  }

  if (EPI == 0) {
#pragma unroll
    for (int i = 0; i < 4; i++)
#pragma unroll
      for (int j = 0; j < 4; j++)
#pragma unroll
        for (int r = 0; r < 4; r++) {
          int m = m0 + wm + i * 16 + quad * 4 + r;
          int n = n0 + wn + j * 16 + l15;
          Cf[(size_t)m * N + n] = acc[i][j][r];
        }
  } else {
    const int qkvsel = n0 >> 11;
    const int h = (n0 >> 7) & 15;
#pragma unroll
    for (int i = 0; i < 4; i++)
#pragma unroll
      for (int j = 0; j < 4; j++) {
        int d = wn + j * 16 + l15;  // 0..127 within head
        if (qkvsel < 2) {
          ushort* dst = (qkvsel == 0) ? C0 : C1;
#pragma unroll
          for (int r = 0; r < 4; r++) {
            int m = m0 + wm + i * 16 + quad * 4 + r;
            int b = m >> 11, s = m & 2047;
            dst[((size_t)(b * 16 + h) * 2048 + s) * 128 + d] = f2bf(acc[i][j][r]);
          }
        } else {
          int m = m0 + wm + i * 16 + quad * 4;
          int b = m >> 11, s = m & 2047;
          ushort4 pk;
          pk.x = f2bf(acc[i][j][0]);
          pk.y = f2bf(acc[i][j][1]);
          pk.z = f2bf(acc[i][j][2]);
          pk.w = f2bf(acc[i][j][3]);
          *(ushort4*)&C2[((size_t)(b * 16 + h) * 128 + d) * 2048 + s] = pk;
        }
      }
  }
}

// ---------------------------------------------------------------- RoPE
// in-place on Q and K planes: [bh][s][128]. Q additionally pre-scaled by
// (1/sqrt(128))*log2(e) so attention can use exp2 with no per-tile scaling.
__global__ __launch_bounds__(256) void rope_kernel(
    ushort* __restrict__ Q, ushort* __restrict__ Kb,
    const float* __restrict__ cosT, const float* __restrict__ sinT) {
  unsigned gid = blockIdx.x * 256u + threadIdx.x;
  int d = gid & 63;
  int s = (gid >> 6) & 2047;
  int bh = (gid >> 17) & 63;
  const bool isK = (gid >> 23) != 0;
  ushort* buf = isK ? Kb : Q;
  const float sc = isK ? 1.0f
                       : 0.08838834764831845f * 1.4426950408889634f;
  size_t base = ((size_t)bh * 2048 + s) * 128;
  float x1 = bf2f(buf[base + d]);
  float x2 = bf2f(buf[base + d + 64]);
  float c = cosT[s * 64 + d];
  float sn = sinT[s * 64 + d];
  buf[base + d] = f2bf((x1 * c - x2 * sn) * sc);
  buf[base + d + 64] = f2bf((x1 * sn + x2 * c) * sc);
}

// ---------------------------------------------------------------- attention
// flash-style causal attention, transposed-score form.
// Grid: 1-D, 2048 blocks, heavy-first: tq = 31-(bid>>6), bh = bid&63.
// Q-tile = 64 rows, 4 waves x 16 q. Per wave: S^T = K.Q^T (q = lane&15),
// per-lane scalar online softmax, P^T -> LDS (b64), O^T = V^T.P^T.
// Q [bh][s][128] (pre-scaled), K [bh][s][128], VT [bh][128][s],
// O -> [b][s][h*128+d] (bf16)
__global__ __launch_bounds__(256, 4) void attn_kernel(
    const ushort* __restrict__ Q, const ushort* __restrict__ Kb,
    const ushort* __restrict__ VT, ushort* __restrict__ O) {
  __shared__ __align__(16) ushort Ks[64 * 128];  // [k_local][d], xor(row&15)
  __shared__ __align__(16) ushort Vs[128 * 64];  // [d][s_local], xor(row&7)
  __shared__ __align__(16) ushort Ps[64 * 64];   // [q_local][k], 8-el grp xor(l15&7)
  const int t = threadIdx.x, lane = t & 63, w = t >> 6;
  const int l15 = lane & 15, quad = lane >> 4;
  const int bid = blockIdx.x;
  const int tq = 31 - (bid >> 6);   // heavy-first
  const int bh = bid & 63;
  const int q0 = tq * 64 + w * 16;
  const int qrow = q0 + l15;        // this lane's q row
  const size_t hbase = (size_t)bh * 2048 * 128;
  const float NEGINF = -__builtin_inff();

  // Q fragments (B-operand): n=q=l15, k=d contiguous 8
  bf16x8 aq[4];
#pragma unroll
  for (int kb = 0; kb < 4; kb++)
    aq[kb] = *(const bf16x8*)&Q[hbase + (size_t)qrow * 128 + kb * 32 + quad * 8];

  float m2 = NEGINF, lsum = 0.f;
  floatx4 oacc[8];  // O^T: row d = dj*16+quad*4+r, col q = l15
  const floatx4 zero = {0.f, 0.f, 0.f, 0.f};
#pragma unroll
  for (int dj = 0; dj < 8; dj++) oacc[dj] = zero;

  const int ntk = tq + 1;

  for (int tk = 0; tk < ntk; tk++) {
    __syncthreads();
#pragma unroll
    for (int it = 0; it < 4; it++) {
      int o = (w * 4 + it) * 64 + lane;
      {  // K tile: 64 rows x 128 el
        int row = o >> 4;
        int c = (o & 15) ^ (row & 15);
        gld16(&Ks[(w * 4 + it) * 512],
              Kb + hbase + (size_t)(tk * 64 + row) * 128 + c * 8);
      }
      {  // V^T tile: 128 rows x 64 el
        int row = o >> 3;
        int c = (o & 7) ^ (row & 7);
        gld16(&Vs[(w * 4 + it) * 512],
              VT + hbase + (size_t)row * 2048 + tk * 64 + c * 8);
      }
    }
    __syncthreads();

    // ---- S^T = K.Q^T : sacc[j] rows k = j*16+quad*4+r, col q = l15
    floatx4 sacc[4];
#pragma unroll
    for (int j = 0; j < 4; j++) sacc[j] = zero;
#pragma unroll
    for (int kb = 0; kb < 4; kb++) {
#pragma unroll
      for (int j = 0; j < 4; j++) {
        int row = j * 16 + l15;
        int c = (kb * 4 + quad) ^ (row & 15);
        bf16x8 kf = *(const bf16x8*)&Ks[row * 128 + c * 8];
        sacc[j] = __builtin_amdgcn_mfma_f32_16x16x32_bf16(kf, aq[kb], sacc[j],
                                                          0, 0, 0);
      }
    }

    // ---- causal mask (diagonal tile only); scores already in log2 domain
    if (tk == tq) {
#pragma unroll
      for (int j = 0; j < 4; j++)
#pragma unroll
        for (int r = 0; r < 4; r++) {
          int kcol = tk * 64 + j * 16 + quad * 4 + r;
          if (kcol > qrow) sacc[j][r] = NEGINF;
        }
    }

    // ---- per-lane scalar online softmax (row q = l15)
    float mx = sacc[0][0];
#pragma unroll
    for (int j = 0; j < 4; j++)
#pragma unroll
      for (int r = 0; r < 4; r++) mx = fmaxf(mx, sacc[j][r]);
    mx = fmaxf(mx, __shfl_xor(mx, 16));
    mx = fmaxf(mx, __shfl_xor(mx, 32));
    float mnew = fmaxf(m2, mx);
    float alpha = __builtin_exp2f(m2 - mnew);
    m2 = mnew;
    float rs = 0.f;
#pragma unroll
    for (int j = 0; j < 4; j++)
#pragma unroll
      for (int r = 0; r < 4; r++) {
        float p = __builtin_exp2f(sacc[j][r] - mnew);
        sacc[j][r] = p;
        rs += p;
      }
    rs += __shfl_xor(rs, 16);
    rs += __shfl_xor(rs, 32);
    lsum = lsum * alpha + rs;
    if (__any(alpha < 1.0f)) {
#pragma unroll
      for (int dj = 0; dj < 8; dj++) oacc[dj] *= alpha;
    }

    // ---- P^T -> LDS: row q_local = w*16+l15, 4 consecutive k per write.
    // 8-element groups swizzled: g' = g ^ (l15&7)
#pragma unroll
    for (int j = 0; j < 4; j++) {
      unsigned lo = pk2bf(sacc[j][0], sacc[j][1]);
      unsigned hi = pk2bf(sacc[j][2], sacc[j][3]);
      int g = j * 2 + (quad >> 1);
      int gp = g ^ (l15 & 7);
      uint2 pv; pv.x = lo; pv.y = hi;
      *(uint2*)&Ps[(w * 16 + l15) * 64 + gp * 8 + (quad & 1) * 4] = pv;
    }

    // ---- O^T += V^T . P^T  (same-wave Ps write->read, per-wave rows)
    bf16x8 bp[2];
#pragma unroll
    for (int kk = 0; kk < 2; kk++) {
      int g = kk * 4 + quad;
      int gp = g ^ (l15 & 7);
      bp[kk] = *(const bf16x8*)&Ps[(w * 16 + l15) * 64 + gp * 8];
    }
#pragma unroll
    for (int kk = 0; kk < 2; kk++)
#pragma unroll
      for (int dj = 0; dj < 8; dj++) {
        int rowd = dj * 16 + l15;
        int c = (kk * 4 + quad) ^ (rowd & 7);
        bf16x8 av = *(const bf16x8*)&Vs[rowd * 64 + c * 8];
        oacc[dj] = __builtin_amdgcn_mfma_f32_16x16x32_bf16(av, bp[kk], oacc[dj],
                                                           0, 0, 0);
      }
  }

  // epilogue: O^T lane holds col q = l15, rows d = dj*16+quad*4+r
  const int b = bh >> 4, h = bh & 15;
  const float rl = 1.0f / lsum;
  const size_t obase = ((size_t)(b * 2048 + qrow)) * 2048 + h * 128;
#pragma unroll
  for (int dj = 0; dj < 8; dj++) {
    ushort4 pk;
    pk.x = f2bf(oacc[dj][0] * rl);
    pk.y = f2bf(oacc[dj][1] * rl);
    pk.z = f2bf(oacc[dj][2] * rl);
    pk.w = f2bf(oacc[dj][3] * rl);
    *(ushort4*)&O[obase + dj * 16 + quad * 4] = pk;
  }
}

// ---------------------------------------------------------------- launch
// All inputs/outputs fp32 (per reference). bf16 scratch:
//   d_out[0 .. 33.5MB)  : xbf (bf16 x), dead before GEMM2 overwrites d_out
//   ws[0, 33.5M)        : wqkvT (GEMM1 only) then Ob (attn -> GEMM2)
//   ws[33.5M, 42.0M)    : woutT
//   ws[42.0M, 75.5M)    : Q   [64][2048][128]
//   ws[75.5M, 109.1M)   : K   [64][2048][128]
//   ws[109.1M, 142.6M)  : VT  [64][128][2048]
extern "C" void kernel_launch(void* const* d_in, const int* in_sizes, int n_in,
                              void* d_out, int out_size, void* d_ws, size_t ws_size,
                              hipStream_t stream) {
  const float* x    = (const float*)d_in[0];
  const float* cosT = (const float*)d_in[1];
  const float* sinT = (const float*)d_in[2];
  const float* wqkv = (const float*)d_in[3];
  const float* wout = (const float*)d_in[4];
  float* out = (float*)d_out;
  char* ws = (char*)d_ws;

  ushort* xbf   = (ushort*)d_out;                      // 8192x2048 bf16 scratch
  ushort* wqkvT = (ushort*)(ws);                       // 6144x2048
  ushort* Ob    = (ushort*)(ws);                       // 8192x2048 (after GEMM1)
  ushort* woutT = (ushort*)(ws + 33554432);            // 2048x2048
  ushort* Qb    = (ushort*)(ws + 41943040);
  ushort* Kbuf  = (ushort*)(ws + 75497472);
  ushort* VTb   = (ushort*)(ws + 109051904);

  cvt_f32_bf16<<<16384, 256, 0, stream>>>(x, xbf);
  transpose_cvt<<<dim3(96, 32), 256, 0, stream>>>(wqkv, wqkvT, 2048, 6144);
  transpose_cvt<<<dim3(32, 32), 256, 0, stream>>>(wout, woutT, 2048, 2048);
  gemm128<1><<<dim3(48, 64), 256, 0, stream>>>(xbf, wqkvT, nullptr,
                                               Qb, Kbuf, VTb, 8192, 6144, 2048);
  rope_kernel<<<65536, 256, 0, stream>>>(Qb, Kbuf, cosT, sinT);
  attn_kernel<<<2048, 256, 0, stream>>>(Qb, Kbuf, VTb, Ob);
  gemm128<0><<<dim3(16, 64), 256, 0, stream>>>(Ob, woutT, out,
                                               nullptr, nullptr, nullptr,
                                               8192, 2048, 2048);
}